// Round 26
// baseline (315.649 us; speedup 1.0000x reference)
//
#include <hip/hip_runtime.h>
#include <hip/hip_bf16.h>

typedef __bf16 bf16;
typedef bf16 bf16x4 __attribute__((ext_vector_type(4)));
typedef bf16 bf16x8 __attribute__((ext_vector_type(8)));
typedef float f32x4 __attribute__((ext_vector_type(4)));

#define B_ 2
#define S_ 2048
#define HID_ 2048
#define NH_ 16
#define HD_ 128
#define M_TOT (B_ * S_)          // 4096
#define RSCALE 0.08838834764831845f   // 1/sqrt(128)
#define LN10000_OVER_64 0.14391156f    // ln(10000)/64

// ---------------- ws layout (bytes) ----------------
#define OFF_XB   0ull
#define OFF_WQT  (OFF_XB  + (size_t)M_TOT*HID_*2)
#define OFF_WKT  (OFF_WQT + (size_t)HID_*HID_*2)   // Wqt/Wkt/Wvt contiguous
#define OFF_WVT  (OFF_WKT + (size_t)HID_*HID_*2)
#define OFF_WOT  (OFF_WVT + (size_t)HID_*HID_*2)
#define OFF_QB   (OFF_WOT + (size_t)HID_*HID_*2)   // Qb/Kb/Vtb contiguous
#define OFF_KB   (OFF_QB  + (size_t)M_TOT*HID_*2)
#define OFF_VTB  (OFF_KB  + (size_t)M_TOT*HID_*2)
#define OFF_AB   (OFF_VTB + (size_t)M_TOT*HID_*2)

// async global -> LDS, 16B per lane. LDS dest must be wave-uniform base.
__device__ __forceinline__ void gload16(const bf16* g, bf16* l) {
    typedef const __attribute__((address_space(1))) unsigned int gu32;
    typedef __attribute__((address_space(3))) unsigned int lu32;
    __builtin_amdgcn_global_load_lds((gu32*)g, (lu32*)l, 16, 0, 0);
}

// ---------------- cast X fp32 -> bf16 ----------------
__global__ __launch_bounds__(256) void cvt_x(const float* __restrict__ x,
                                             bf16* __restrict__ o) {
    size_t i = ((size_t)blockIdx.x * 256 + threadIdx.x) * 4;
    float4 v = *(const float4*)(x + i);
    bf16x4 r; r[0] = (bf16)v.x; r[1] = (bf16)v.y; r[2] = (bf16)v.z; r[3] = (bf16)v.w;
    *(bf16x4*)(o + i) = r;
}

// -------- transpose + cast W (K,N) fp32 -> Wt (N,K) bf16 --------
__global__ __launch_bounds__(256) void trans_w(const float* w0, const float* w1,
                                               const float* w2, const float* w3,
                                               bf16* o0, bf16* o1, bf16* o2, bf16* o3) {
    const float* W; bf16* O;
    switch (blockIdx.z) {
        case 0: W = w0; O = o0; break;
        case 1: W = w1; O = o1; break;
        case 2: W = w2; O = o2; break;
        default: W = w3; O = o3; break;
    }
    __shared__ float t[64][65];
    int tid = threadIdx.x;
    int nt0 = blockIdx.x * 64, kt0 = blockIdx.y * 64;
    #pragma unroll
    for (int p = 0; p < 4; ++p) {
        int r = p * 16 + (tid >> 4);
        int c = (tid & 15) * 4;
        float4 v = *(const float4*)(W + (size_t)(kt0 + r) * HID_ + nt0 + c);
        t[r][c + 0] = v.x; t[r][c + 1] = v.y; t[r][c + 2] = v.z; t[r][c + 3] = v.w;
    }
    __syncthreads();
    #pragma unroll
    for (int p = 0; p < 4; ++p) {
        int rr = p * 16 + (tid >> 4);
        int cc = (tid & 15) * 4;
        bf16x4 v;
        v[0] = (bf16)t[cc + 0][rr]; v[1] = (bf16)t[cc + 1][rr];
        v[2] = (bf16)t[cc + 2][rr]; v[3] = (bf16)t[cc + 3][rr];
        *(bf16x4*)(O + (size_t)(nt0 + rr) * HID_ + kt0 + cc) = v;
    }
}

// ---------------- fused QKV GEMM (m97 structure + T2 swizzle) ----------------
// sel==2 (V) epilogue routes the 128x128 tile through LDS (aliasing the dead
// staging buffers) so global stores are contiguous 16B runs instead of
// 2B/4KB-stride scatter.
__global__ __launch_bounds__(256) void gemm_qkv(const bf16* __restrict__ A,
                                                const bf16* __restrict__ Wt3,
                                                const float* __restrict__ bq,
                                                const float* __restrict__ bk,
                                                const float* __restrict__ bv,
                                                const int* __restrict__ pos_ids,
                                                bf16* __restrict__ out3) {
    __shared__ bf16 smem[2][128][64];     // [0]=Al, [1]=Bl; aliased as 128x128 V-tile
    bf16 (*Al)[64] = smem[0];
    bf16 (*Bl)[64] = smem[1];
    bf16* tile = &smem[0][0][0];          // 16384 elems = 128x128
    const int tid = threadIdx.x;
    const int l = tid & 63, w = tid >> 6;
    const int ln = l & 15, lg = l >> 4;
    const int bm = blockIdx.y;
    const int sel = blockIdx.x >> 4, bnn = blockIdx.x & 15;
    const bf16* Bt = Wt3 + (size_t)sel * HID_ * HID_ + (size_t)bnn * 128 * HID_;
    const float* bias = sel == 0 ? bq : (sel == 1 ? bk : bv);
    const int swz = (ln & 7) * 8;                  // read-side XOR (elements)

    f32x4 acc[2][8] = {};

    for (int k0 = 0; k0 < HID_; k0 += 64) {
        __syncthreads();
        #pragma unroll
        for (int j = 0; j < 4; ++j) {
            int r0 = w * 32 + j * 8;
            int r = r0 + (l >> 3);
            int c = (((l & 7) ^ ((l >> 3) & 7))) * 8;   // source-side swizzle
            gload16(A  + (size_t)(bm * 128 + r) * HID_ + k0 + c, &Al[r0][0]);
            gload16(Bt + (size_t)r * HID_ + k0 + c, &Bl[r0][0]);
        }
        __syncthreads();
        #pragma unroll
        for (int kk = 0; kk < 2; ++kk) {
            bf16x8 af[2], bfv[8];
            #pragma unroll
            for (int fm = 0; fm < 2; ++fm)
                af[fm] = *(const bf16x8*)&Al[w * 32 + fm * 16 + ln][(kk * 32 + lg * 8) ^ swz];
            #pragma unroll
            for (int fn = 0; fn < 8; ++fn)
                bfv[fn] = *(const bf16x8*)&Bl[fn * 16 + ln][(kk * 32 + lg * 8) ^ swz];
            #pragma unroll
            for (int fm = 0; fm < 2; ++fm)
                #pragma unroll
                for (int fn = 0; fn < 8; ++fn)
                    acc[fm][fn] = __builtin_amdgcn_mfma_f32_16x16x32_bf16(
                        af[fm], bfv[fn], acc[fm][fn], 0, 0, 0);
        }
    }

    if (sel == 2) {
        // ---- V epilogue: LDS transpose for coalesced V^T stores ----
        __syncthreads();                           // staging buffers now dead
        #pragma unroll
        for (int fm = 0; fm < 2; ++fm)
            #pragma unroll
            for (int i = 0; i < 4; ++i) {
                int s_local = w * 32 + fm * 16 + lg * 4 + i;
                #pragma unroll
                for (int fn = 0; fn < 8; ++fn) {
                    int d = fn * 16 + ln;
                    float v = acc[fm][fn][i] + bias[bnn * 128 + d];
                    tile[d * 128 + (s_local ^ ((d & 7) * 8))] = (bf16)v;
                }
            }
        __syncthreads();
        const int b = (bm * 128) >> 11;
        const int s_base = (bm * 128) & (S_ - 1);
        bf16* O = out3 + 2 * (size_t)M_TOT * HID_
                + ((size_t)(b * NH_ + bnn) * HD_) * S_;
        const int sc = tid & 15;                   // 8-elem chunk within 128-s row
        #pragma unroll
        for (int p = 0; p < 8; ++p) {
            int d = p * 16 + (tid >> 4);
            bf16x8 v = *(const bf16x8*)&tile[d * 128 + ((sc * 8) ^ ((d & 7) * 8))];
            *(bf16x8*)(O + (size_t)d * S_ + s_base + sc * 8) = v;
        }
        return;
    }

    #pragma unroll
    for (int fm = 0; fm < 2; ++fm) {
        #pragma unroll
        for (int i = 0; i < 4; ++i) {
            int m_g = bm * 128 + w * 32 + fm * 16 + lg * 4 + i;
            int b = m_g >> 11, s = m_g & (S_ - 1);
            int pos = pos_ids[m_g];
            pos = pos < 0 ? 0 : (pos > 4095 ? 4095 : pos);
            size_t base = ((size_t)(b * NH_ + bnn) * S_ + s) * HD_;
            bf16* O = out3 + (size_t)sel * M_TOT * HID_;
            #pragma unroll
            for (int fn = 0; fn < 4; ++fn) {
                int j = fn * 16 + ln;
                float x1 = acc[fm][fn][i]     + bias[bnn * 128 + j];
                float x2 = acc[fm][fn + 4][i] + bias[bnn * 128 + j + 64];
                float invf = __expf(-(float)j * LN10000_OVER_64);
                float ang = (float)pos * invf;
                float sn, cs;
                __sincosf(ang, &sn, &cs);
                float y1 = x1 * cs - x2 * sn;
                float y2 = x2 * cs + x1 * sn;
                if (sel == 0) { y1 *= RSCALE; y2 *= RSCALE; }
                O[base + j]      = (bf16)y1;
                O[base + j + 64] = (bf16)y2;
            }
        }
    }
}

// ---------------- O-projection GEMM (fp32 out, swizzle + XCD map) ----------------
__global__ __launch_bounds__(256) void gemm_o(const bf16* __restrict__ A,
                                              const bf16* __restrict__ Bt0,
                                              const float* __restrict__ bias,
                                              float* __restrict__ out) {
    __shared__ bf16 Al[128][64];
    __shared__ bf16 Bl[128][64];
    const int tid = threadIdx.x;
    const int l = tid & 63, w = tid >> 6;
    const int ln = l & 15, lg = l >> 4;
    const int id = blockIdx.x;
    const int xcd = id & 7, k = id >> 3;
    const int bn = xcd * 2 + (k & 1);
    const int bm = k >> 1;
    const bf16* Bt = Bt0 + (size_t)bn * 128 * HID_;
    const int swz = (ln & 7) * 8;

    f32x4 acc[2][8] = {};

    for (int k0 = 0; k0 < HID_; k0 += 64) {
        __syncthreads();
        #pragma unroll
        for (int j = 0; j < 4; ++j) {
            int r0 = w * 32 + j * 8;
            int r = r0 + (l >> 3);
            int c = (((l & 7) ^ ((l >> 3) & 7))) * 8;
            gload16(A  + (size_t)(bm * 128 + r) * HID_ + k0 + c, &Al[r0][0]);
            gload16(Bt + (size_t)r * HID_ + k0 + c, &Bl[r0][0]);
        }
        __syncthreads();
        #pragma unroll
        for (int kk = 0; kk < 2; ++kk) {
            bf16x8 af[2], bfv[8];
            #pragma unroll
            for (int fm = 0; fm < 2; ++fm)
                af[fm] = *(const bf16x8*)&Al[w * 32 + fm * 16 + ln][(kk * 32 + lg * 8) ^ swz];
            #pragma unroll
            for (int fn = 0; fn < 8; ++fn)
                bfv[fn] = *(const bf16x8*)&Bl[fn * 16 + ln][(kk * 32 + lg * 8) ^ swz];
            #pragma unroll
            for (int fm = 0; fm < 2; ++fm)
                #pragma unroll
                for (int fn = 0; fn < 8; ++fn)
                    acc[fm][fn] = __builtin_amdgcn_mfma_f32_16x16x32_bf16(
                        af[fm], bfv[fn], acc[fm][fn], 0, 0, 0);
        }
    }

    #pragma unroll
    for (int fm = 0; fm < 2; ++fm)
        #pragma unroll
        for (int i = 0; i < 4; ++i) {
            int m_g = bm * 128 + w * 32 + fm * 16 + lg * 4 + i;
            #pragma unroll
            for (int fn = 0; fn < 8; ++fn) {
                int n_g = bn * 128 + fn * 16 + ln;
                out[(size_t)m_g * HID_ + n_g] = acc[fm][fn][i] + bias[n_g];
            }
        }
}

// -------- flash attention: double-buffered, single-barrier, swizzled, defer-max --------
__global__ __launch_bounds__(512) void attn_k(const bf16* __restrict__ Q,
                                              const bf16* __restrict__ K,
                                              const bf16* __restrict__ Vt,
                                              bf16* __restrict__ O) {
    __shared__ bf16 Kl[2][64][128];
    __shared__ bf16 Vl[2][128][64];
    __shared__ bf16 Pl[8][16][64];
    const int tid = threadIdx.x;
    const int l = tid & 63, w = tid >> 6;          // 8 waves
    const int ln = l & 15, lg = l >> 4;
    const int bid = blockIdx.x;                    // 512 linear
    const int j  = 15 - (bid >> 5);                // heavy q-tiles first
    const int bh = bid & 31;
    const int nkt = 2 * j + 2;                     // 64-key tiles

    const bf16* Qb = Q  + (size_t)bh * S_ * HD_;
    const bf16* Kb = K  + (size_t)bh * S_ * HD_;
    const bf16* Vb = Vt + (size_t)bh * S_ * HD_;   // (HD, S) per bh
    const int b = bh >> 4, h = bh & (NH_ - 1);

    const int qrow = j * 128 + w * 16 + ln;
    const int qg0  = j * 128 + w * 16 + lg * 4;
    const int swzP = (ln & 7) * 8;

    bf16x8 qf[4];
    #pragma unroll
    for (int kk = 0; kk < 4; ++kk)
        qf[kk] = *(const bf16x8*)(Qb + (size_t)qrow * HD_ + kk * 32 + lg * 8);

    float m_run[4], l_run[4];
    #pragma unroll
    for (int i = 0; i < 4; ++i) { m_run[i] = -1e30f; l_run[i] = 0.f; }
    f32x4 oacc[8] = {};

    uint4 kr[2], vr[2];
    // ---- prologue: tile 0 -> regs -> buf0; tile 1 -> regs ----
    #pragma unroll
    for (int m = 0; m < 2; ++m) {
        int f = m * 512 + tid;
        kr[m] = *(const uint4*)(Kb + (size_t)(f >> 4) * HD_ + (f & 15) * 8);
        vr[m] = *(const uint4*)(Vb + (size_t)(f >> 3) * S_ + (f & 7) * 8);
    }
    #pragma unroll
    for (int m = 0; m < 2; ++m) {
        int f = m * 512 + tid;
        int r = f >> 4,  c = f & 15;
        int rv = f >> 3, cv = f & 7;
        *(uint4*)&Kl[0][r][(c ^ (r & 7)) * 8] = kr[m];
        *(uint4*)&Vl[0][rv][(cv ^ (rv & 7)) * 8] = vr[m];
    }
    if (nkt > 1) {
        #pragma unroll
        for (int m = 0; m < 2; ++m) {
            int f = m * 512 + tid;
            kr[m] = *(const uint4*)(Kb + (size_t)(64 + (f >> 4)) * HD_ + (f & 15) * 8);
            vr[m] = *(const uint4*)(Vb + (size_t)(f >> 3) * S_ + 64 + (f & 7) * 8);
        }
    }
    __syncthreads();

    for (int kt = 0; kt < nkt; ++kt) {
        const int cur = kt & 1;
        if (kt + 1 < nkt) {                        // write tile kt+1 -> other buf
            #pragma unroll
            for (int m = 0; m < 2; ++m) {
                int f = m * 512 + tid;
                int r = f >> 4,  c = f & 15;
                int rv = f >> 3, cv = f & 7;
                *(uint4*)&Kl[cur ^ 1][r][(c ^ (r & 7)) * 8] = kr[m];
                *(uint4*)&Vl[cur ^ 1][rv][(cv ^ (rv & 7)) * 8] = vr[m];
            }
        }
        if (kt + 2 < nkt) {                        // prefetch tile kt+2 -> regs
            #pragma unroll
            for (int m = 0; m < 2; ++m) {
                int f = m * 512 + tid;
                kr[m] = *(const uint4*)(Kb + (size_t)((kt + 2) * 64 + (f >> 4)) * HD_ + (f & 15) * 8);
                vr[m] = *(const uint4*)(Vb + (size_t)(f >> 3) * S_ + (kt + 2) * 64 + (f & 7) * 8);
            }
        }

        f32x4 sacc[4] = {};
        __builtin_amdgcn_s_setprio(1);
        #pragma unroll
        for (int kk = 0; kk < 4; ++kk) {
            bf16x8 kf[4];
            #pragma unroll
            for (int n = 0; n < 4; ++n)
                kf[n] = *(const bf16x8*)&Kl[cur][n * 16 + ln][(kk * 32 + lg * 8) ^ swzP];
            #pragma unroll
            for (int n = 0; n < 4; ++n)
                sacc[n] = __builtin_amdgcn_mfma_f32_16x16x32_bf16(qf[kk], kf[n], sacc[n], 0, 0, 0);
        }
        __builtin_amdgcn_s_setprio(0);

        if (kt >= 2 * j) {                         // diagonal band: causal mask
            #pragma unroll
            for (int n = 0; n < 4; ++n)
                #pragma unroll
                for (int i = 0; i < 4; ++i) {
                    int kg = kt * 64 + n * 16 + ln;
                    if (kg > qg0 + i) sacc[n][i] = -1e30f;
                }
        }

        float mt[4];
        #pragma unroll
        for (int i = 0; i < 4; ++i) {
            mt[i] = fmaxf(fmaxf(sacc[0][i], sacc[1][i]), fmaxf(sacc[2][i], sacc[3][i]));
            #pragma unroll
            for (int d = 1; d < 16; d <<= 1)
                mt[i] = fmaxf(mt[i], __shfl_xor(mt[i], d));
        }
        // T13 defer-max: skip rescale when all tile maxima within +8 of running max
        bool ok = true;
        #pragma unroll
        for (int i = 0; i < 4; ++i) ok = ok && (mt[i] <= m_run[i] + 8.f);
        if (!__all(ok)) {
            #pragma unroll
            for (int i = 0; i < 4; ++i) {
                float mnew = fmaxf(m_run[i], mt[i]);
                float scale = __expf(m_run[i] - mnew);
                m_run[i] = mnew;
                l_run[i] *= scale;
                #pragma unroll
                for (int dn = 0; dn < 8; ++dn)
                    oacc[dn][i] *= scale;
            }
        }
        float rs[4] = {0.f, 0.f, 0.f, 0.f};
        #pragma unroll
        for (int n = 0; n < 4; ++n)
            #pragma unroll
            for (int i = 0; i < 4; ++i) {
                float p = __expf(sacc[n][i] - m_run[i]);
                sacc[n][i] = p;
                rs[i] += p;
            }
        // P -> per-wave LDS (swizzled rows)
        #pragma unroll
        for (int n = 0; n < 4; ++n)
            #pragma unroll
            for (int i = 0; i < 4; ++i)
                Pl[w][lg * 4 + i][(n * 16 + ln) ^ (((lg * 4 + i) & 7) * 8)] = (bf16)sacc[n][i];

        #pragma unroll
        for (int i = 0; i < 4; ++i) {
            #pragma unroll
            for (int d = 1; d < 16; d <<= 1)
                rs[i] += __shfl_xor(rs[i], d);
            l_run[i] += rs[i];
        }

        __builtin_amdgcn_s_setprio(1);
        #pragma unroll
        for (int kk = 0; kk < 2; ++kk) {
            bf16x8 pf = *(const bf16x8*)&Pl[w][ln][(kk * 32 + lg * 8) ^ swzP];
            #pragma unroll
            for (int dn = 0; dn < 8; ++dn) {
                bf16x8 vf = *(const bf16x8*)&Vl[cur][dn * 16 + ln][(kk * 32 + lg * 8) ^ swzP];
                oacc[dn] = __builtin_amdgcn_mfma_f32_16x16x32_bf16(pf, vf, oacc[dn], 0, 0, 0);
            }
        }
        __builtin_amdgcn_s_setprio(0);

        __syncthreads();                           // seals buf[cur^1] writes + buf[cur] reads
    }

    #pragma unroll
    for (int i = 0; i < 4; ++i) {
        float inv = 1.0f / l_run[i];
        int s = j * 128 + w * 16 + lg * 4 + i;
        #pragma unroll
        for (int dn = 0; dn < 8; ++dn) {
            int d = dn * 16 + ln;
            O[((size_t)(b * S_ + s)) * HID_ + h * HD_ + d] = (bf16)(oacc[dn][i] * inv);
        }
    }
}

extern "C" void kernel_launch(void* const* d_in, const int* in_sizes, int n_in,
                              void* d_out, int out_size, void* d_ws, size_t ws_size,
                              hipStream_t stream) {
    const float* X    = (const float*)d_in[0];
    const int*   pos  = (const int*)d_in[2];
    const float* Wq   = (const float*)d_in[3];
    const float* bq   = (const float*)d_in[4];
    const float* Wk   = (const float*)d_in[5];
    const float* bk   = (const float*)d_in[6];
    const float* Wv   = (const float*)d_in[7];
    const float* bv   = (const float*)d_in[8];
    const float* Wo   = (const float*)d_in[9];
    const float* bo   = (const float*)d_in[10];
    float* Out = (float*)d_out;

    char* ws = (char*)d_ws;
    bf16* Xb  = (bf16*)(ws + OFF_XB);
    bf16* Wqt = (bf16*)(ws + OFF_WQT);
    bf16* Wkt = (bf16*)(ws + OFF_WKT);
    bf16* Wvt = (bf16*)(ws + OFF_WVT);
    bf16* Wot = (bf16*)(ws + OFF_WOT);
    bf16* Qb  = (bf16*)(ws + OFF_QB);
    bf16* Kb  = (bf16*)(ws + OFF_KB);
    bf16* Vtb = (bf16*)(ws + OFF_VTB);
    bf16* Ab  = (bf16*)(ws + OFF_AB);

    cvt_x<<<(M_TOT * HID_) / (256 * 4), 256, 0, stream>>>(X, Xb);
    trans_w<<<dim3(32, 32, 4), 256, 0, stream>>>(Wq, Wk, Wv, Wo, Wqt, Wkt, Wvt, Wot);

    gemm_qkv<<<dim3(48, M_TOT / 128), 256, 0, stream>>>(Xb, Wqt, bq, bk, bv, pos, Qb);

    attn_k<<<dim3(512), 512, 0, stream>>>(Qb, Kb, Vtb, Ab);

    gemm_o<<<dim3(512), 256, 0, stream>>>(Ab, Wot, bo, Out);
}

// Round 27
// 315.324 us; speedup vs baseline: 1.0010x; 1.0010x over previous
//
#include <hip/hip_runtime.h>
#include <hip/hip_bf16.h>

typedef __bf16 bf16;
typedef bf16 bf16x4 __attribute__((ext_vector_type(4)));
typedef bf16 bf16x8 __attribute__((ext_vector_type(8)));
typedef float f32x4 __attribute__((ext_vector_type(4)));

#define B_ 2
#define S_ 2048
#define HID_ 2048
#define NH_ 16
#define HD_ 128
#define M_TOT (B_ * S_)          // 4096
#define RSCALE 0.08838834764831845f   // 1/sqrt(128)
#define LN10000_OVER_64 0.14391156f    // ln(10000)/64

// ---------------- ws layout (bytes) ----------------
#define OFF_XB   0ull
#define OFF_WQT  (OFF_XB  + (size_t)M_TOT*HID_*2)
#define OFF_WKT  (OFF_WQT + (size_t)HID_*HID_*2)   // Wqt/Wkt/Wvt contiguous
#define OFF_WVT  (OFF_WKT + (size_t)HID_*HID_*2)
#define OFF_WOT  (OFF_WVT + (size_t)HID_*HID_*2)
#define OFF_QB   (OFF_WOT + (size_t)HID_*HID_*2)   // Qb/Kb/Vtb contiguous
#define OFF_KB   (OFF_QB  + (size_t)M_TOT*HID_*2)
#define OFF_VTB  (OFF_KB  + (size_t)M_TOT*HID_*2)
#define OFF_AB   (OFF_VTB + (size_t)M_TOT*HID_*2)

// async global -> LDS, 16B per lane. LDS dest must be wave-uniform base.
__device__ __forceinline__ void gload16(const bf16* g, bf16* l) {
    typedef const __attribute__((address_space(1))) unsigned int gu32;
    typedef __attribute__((address_space(3))) unsigned int lu32;
    __builtin_amdgcn_global_load_lds((gu32*)g, (lu32*)l, 16, 0, 0);
}

// ---------------- cast X fp32 -> bf16 ----------------
__global__ __launch_bounds__(256) void cvt_x(const float* __restrict__ x,
                                             bf16* __restrict__ o) {
    size_t i = ((size_t)blockIdx.x * 256 + threadIdx.x) * 4;
    float4 v = *(const float4*)(x + i);
    bf16x4 r; r[0] = (bf16)v.x; r[1] = (bf16)v.y; r[2] = (bf16)v.z; r[3] = (bf16)v.w;
    *(bf16x4*)(o + i) = r;
}

// -------- transpose + cast W (K,N) fp32 -> Wt (N,K) bf16 --------
__global__ __launch_bounds__(256) void trans_w(const float* w0, const float* w1,
                                               const float* w2, const float* w3,
                                               bf16* o0, bf16* o1, bf16* o2, bf16* o3) {
    const float* W; bf16* O;
    switch (blockIdx.z) {
        case 0: W = w0; O = o0; break;
        case 1: W = w1; O = o1; break;
        case 2: W = w2; O = o2; break;
        default: W = w3; O = o3; break;
    }
    __shared__ float t[64][65];
    int tid = threadIdx.x;
    int nt0 = blockIdx.x * 64, kt0 = blockIdx.y * 64;
    #pragma unroll
    for (int p = 0; p < 4; ++p) {
        int r = p * 16 + (tid >> 4);
        int c = (tid & 15) * 4;
        float4 v = *(const float4*)(W + (size_t)(kt0 + r) * HID_ + nt0 + c);
        t[r][c + 0] = v.x; t[r][c + 1] = v.y; t[r][c + 2] = v.z; t[r][c + 3] = v.w;
    }
    __syncthreads();
    #pragma unroll
    for (int p = 0; p < 4; ++p) {
        int rr = p * 16 + (tid >> 4);
        int cc = (tid & 15) * 4;
        bf16x4 v;
        v[0] = (bf16)t[cc + 0][rr]; v[1] = (bf16)t[cc + 1][rr];
        v[2] = (bf16)t[cc + 2][rr]; v[3] = (bf16)t[cc + 3][rr];
        *(bf16x4*)(O + (size_t)(nt0 + rr) * HID_ + kt0 + cc) = v;
    }
}

// ---------------- fused QKV GEMM (m97 structure + T2 swizzle) ----------------
// sel==2 (V) epilogue routes the 128x128 tile through LDS (aliasing the dead
// staging buffers) so global stores are contiguous 16B runs instead of
// 2B/4KB-stride scatter.
__global__ __launch_bounds__(256) void gemm_qkv(const bf16* __restrict__ A,
                                                const bf16* __restrict__ Wt3,
                                                const float* __restrict__ bq,
                                                const float* __restrict__ bk,
                                                const float* __restrict__ bv,
                                                const int* __restrict__ pos_ids,
                                                bf16* __restrict__ out3) {
    __shared__ bf16 smem[2][128][64];     // [0]=Al, [1]=Bl; aliased as 128x128 V-tile
    bf16 (*Al)[64] = smem[0];
    bf16 (*Bl)[64] = smem[1];
    bf16* tile = &smem[0][0][0];          // 16384 elems = 128x128
    const int tid = threadIdx.x;
    const int l = tid & 63, w = tid >> 6;
    const int ln = l & 15, lg = l >> 4;
    const int bm = blockIdx.y;
    const int sel = blockIdx.x >> 4, bnn = blockIdx.x & 15;
    const bf16* Bt = Wt3 + (size_t)sel * HID_ * HID_ + (size_t)bnn * 128 * HID_;
    const float* bias = sel == 0 ? bq : (sel == 1 ? bk : bv);
    const int swz = (ln & 7) * 8;                  // read-side XOR (elements)

    f32x4 acc[2][8] = {};

    for (int k0 = 0; k0 < HID_; k0 += 64) {
        __syncthreads();
        #pragma unroll
        for (int j = 0; j < 4; ++j) {
            int r0 = w * 32 + j * 8;
            int r = r0 + (l >> 3);
            int c = (((l & 7) ^ ((l >> 3) & 7))) * 8;   // source-side swizzle
            gload16(A  + (size_t)(bm * 128 + r) * HID_ + k0 + c, &Al[r0][0]);
            gload16(Bt + (size_t)r * HID_ + k0 + c, &Bl[r0][0]);
        }
        __syncthreads();
        #pragma unroll
        for (int kk = 0; kk < 2; ++kk) {
            bf16x8 af[2], bfv[8];
            #pragma unroll
            for (int fm = 0; fm < 2; ++fm)
                af[fm] = *(const bf16x8*)&Al[w * 32 + fm * 16 + ln][(kk * 32 + lg * 8) ^ swz];
            #pragma unroll
            for (int fn = 0; fn < 8; ++fn)
                bfv[fn] = *(const bf16x8*)&Bl[fn * 16 + ln][(kk * 32 + lg * 8) ^ swz];
            #pragma unroll
            for (int fm = 0; fm < 2; ++fm)
                #pragma unroll
                for (int fn = 0; fn < 8; ++fn)
                    acc[fm][fn] = __builtin_amdgcn_mfma_f32_16x16x32_bf16(
                        af[fm], bfv[fn], acc[fm][fn], 0, 0, 0);
        }
    }

    if (sel == 2) {
        // ---- V epilogue: LDS transpose for coalesced V^T stores ----
        __syncthreads();                           // staging buffers now dead
        #pragma unroll
        for (int fm = 0; fm < 2; ++fm)
            #pragma unroll
            for (int i = 0; i < 4; ++i) {
                int s_local = w * 32 + fm * 16 + lg * 4 + i;
                #pragma unroll
                for (int fn = 0; fn < 8; ++fn) {
                    int d = fn * 16 + ln;
                    float v = acc[fm][fn][i] + bias[bnn * 128 + d];
                    tile[d * 128 + (s_local ^ ((d & 7) * 8))] = (bf16)v;
                }
            }
        __syncthreads();
        const int b = (bm * 128) >> 11;
        const int s_base = (bm * 128) & (S_ - 1);
        bf16* O = out3 + 2 * (size_t)M_TOT * HID_
                + ((size_t)(b * NH_ + bnn) * HD_) * S_;
        const int sc = tid & 15;                   // 8-elem chunk within 128-s row
        #pragma unroll
        for (int p = 0; p < 8; ++p) {
            int d = p * 16 + (tid >> 4);
            bf16x8 v = *(const bf16x8*)&tile[d * 128 + ((sc * 8) ^ ((d & 7) * 8))];
            *(bf16x8*)(O + (size_t)d * S_ + s_base + sc * 8) = v;
        }
        return;
    }

    #pragma unroll
    for (int fm = 0; fm < 2; ++fm) {
        #pragma unroll
        for (int i = 0; i < 4; ++i) {
            int m_g = bm * 128 + w * 32 + fm * 16 + lg * 4 + i;
            int b = m_g >> 11, s = m_g & (S_ - 1);
            int pos = pos_ids[m_g];
            pos = pos < 0 ? 0 : (pos > 4095 ? 4095 : pos);
            size_t base = ((size_t)(b * NH_ + bnn) * S_ + s) * HD_;
            bf16* O = out3 + (size_t)sel * M_TOT * HID_;
            #pragma unroll
            for (int fn = 0; fn < 4; ++fn) {
                int j = fn * 16 + ln;
                float x1 = acc[fm][fn][i]     + bias[bnn * 128 + j];
                float x2 = acc[fm][fn + 4][i] + bias[bnn * 128 + j + 64];
                float invf = __expf(-(float)j * LN10000_OVER_64);
                float ang = (float)pos * invf;
                float sn, cs;
                __sincosf(ang, &sn, &cs);
                float y1 = x1 * cs - x2 * sn;
                float y2 = x2 * cs + x1 * sn;
                if (sel == 0) { y1 *= RSCALE; y2 *= RSCALE; }
                O[base + j]      = (bf16)y1;
                O[base + j + 64] = (bf16)y2;
            }
        }
    }
}

// ---------------- O-projection GEMM (fp32 out, swizzle + XCD map) ----------------
__global__ __launch_bounds__(256) void gemm_o(const bf16* __restrict__ A,
                                              const bf16* __restrict__ Bt0,
                                              const float* __restrict__ bias,
                                              float* __restrict__ out) {
    __shared__ bf16 Al[128][64];
    __shared__ bf16 Bl[128][64];
    const int tid = threadIdx.x;
    const int l = tid & 63, w = tid >> 6;
    const int ln = l & 15, lg = l >> 4;
    const int id = blockIdx.x;
    const int xcd = id & 7, k = id >> 3;
    const int bn = xcd * 2 + (k & 1);
    const int bm = k >> 1;
    const bf16* Bt = Bt0 + (size_t)bn * 128 * HID_;
    const int swz = (ln & 7) * 8;

    f32x4 acc[2][8] = {};

    for (int k0 = 0; k0 < HID_; k0 += 64) {
        __syncthreads();
        #pragma unroll
        for (int j = 0; j < 4; ++j) {
            int r0 = w * 32 + j * 8;
            int r = r0 + (l >> 3);
            int c = (((l & 7) ^ ((l >> 3) & 7))) * 8;
            gload16(A  + (size_t)(bm * 128 + r) * HID_ + k0 + c, &Al[r0][0]);
            gload16(Bt + (size_t)r * HID_ + k0 + c, &Bl[r0][0]);
        }
        __syncthreads();
        #pragma unroll
        for (int kk = 0; kk < 2; ++kk) {
            bf16x8 af[2], bfv[8];
            #pragma unroll
            for (int fm = 0; fm < 2; ++fm)
                af[fm] = *(const bf16x8*)&Al[w * 32 + fm * 16 + ln][(kk * 32 + lg * 8) ^ swz];
            #pragma unroll
            for (int fn = 0; fn < 8; ++fn)
                bfv[fn] = *(const bf16x8*)&Bl[fn * 16 + ln][(kk * 32 + lg * 8) ^ swz];
            #pragma unroll
            for (int fm = 0; fm < 2; ++fm)
                #pragma unroll
                for (int fn = 0; fn < 8; ++fn)
                    acc[fm][fn] = __builtin_amdgcn_mfma_f32_16x16x32_bf16(
                        af[fm], bfv[fn], acc[fm][fn], 0, 0, 0);
        }
    }

    #pragma unroll
    for (int fm = 0; fm < 2; ++fm)
        #pragma unroll
        for (int i = 0; i < 4; ++i) {
            int m_g = bm * 128 + w * 32 + fm * 16 + lg * 4 + i;
            #pragma unroll
            for (int fn = 0; fn < 8; ++fn) {
                int n_g = bn * 128 + fn * 16 + ln;
                out[(size_t)m_g * HID_ + n_g] = acc[fm][fn][i] + bias[n_g];
            }
        }
}

// -------- flash attention: double-buffered, single-barrier, swizzled, defer-max --------
__global__ __launch_bounds__(512) void attn_k(const bf16* __restrict__ Q,
                                              const bf16* __restrict__ K,
                                              const bf16* __restrict__ Vt,
                                              bf16* __restrict__ O) {
    __shared__ bf16 Kl[2][64][128];
    __shared__ bf16 Vl[2][128][64];
    __shared__ bf16 Pl[8][16][64];
    const int tid = threadIdx.x;
    const int l = tid & 63, w = tid >> 6;          // 8 waves
    const int ln = l & 15, lg = l >> 4;
    const int bid = blockIdx.x;                    // 512 linear
    const int j  = 15 - (bid >> 5);                // heavy q-tiles first
    const int bh = bid & 31;
    const int nkt = 2 * j + 2;                     // 64-key tiles

    const bf16* Qb = Q  + (size_t)bh * S_ * HD_;
    const bf16* Kb = K  + (size_t)bh * S_ * HD_;
    const bf16* Vb = Vt + (size_t)bh * S_ * HD_;   // (HD, S) per bh
    const int b = bh >> 4, h = bh & (NH_ - 1);

    const int qrow = j * 128 + w * 16 + ln;
    const int qg0  = j * 128 + w * 16 + lg * 4;
    const int swzP = (ln & 7) * 8;

    bf16x8 qf[4];
    #pragma unroll
    for (int kk = 0; kk < 4; ++kk)
        qf[kk] = *(const bf16x8*)(Qb + (size_t)qrow * HD_ + kk * 32 + lg * 8);

    float m_run[4], l_run[4];
    #pragma unroll
    for (int i = 0; i < 4; ++i) { m_run[i] = -1e30f; l_run[i] = 0.f; }
    f32x4 oacc[8] = {};

    uint4 kr[2], vr[2];
    // ---- prologue: tile 0 -> regs -> buf0; tile 1 -> regs ----
    #pragma unroll
    for (int m = 0; m < 2; ++m) {
        int f = m * 512 + tid;
        kr[m] = *(const uint4*)(Kb + (size_t)(f >> 4) * HD_ + (f & 15) * 8);
        vr[m] = *(const uint4*)(Vb + (size_t)(f >> 3) * S_ + (f & 7) * 8);
    }
    #pragma unroll
    for (int m = 0; m < 2; ++m) {
        int f = m * 512 + tid;
        int r = f >> 4,  c = f & 15;
        int rv = f >> 3, cv = f & 7;
        *(uint4*)&Kl[0][r][(c ^ (r & 7)) * 8] = kr[m];
        *(uint4*)&Vl[0][rv][(cv ^ (rv & 7)) * 8] = vr[m];
    }
    if (nkt > 1) {
        #pragma unroll
        for (int m = 0; m < 2; ++m) {
            int f = m * 512 + tid;
            kr[m] = *(const uint4*)(Kb + (size_t)(64 + (f >> 4)) * HD_ + (f & 15) * 8);
            vr[m] = *(const uint4*)(Vb + (size_t)(f >> 3) * S_ + 64 + (f & 7) * 8);
        }
    }
    __syncthreads();

    for (int kt = 0; kt < nkt; ++kt) {
        const int cur = kt & 1;
        if (kt + 1 < nkt) {                        // write tile kt+1 -> other buf
            #pragma unroll
            for (int m = 0; m < 2; ++m) {
                int f = m * 512 + tid;
                int r = f >> 4,  c = f & 15;
                int rv = f >> 3, cv = f & 7;
                *(uint4*)&Kl[cur ^ 1][r][(c ^ (r & 7)) * 8] = kr[m];
                *(uint4*)&Vl[cur ^ 1][rv][(cv ^ (rv & 7)) * 8] = vr[m];
            }
        }
        if (kt + 2 < nkt) {                        // prefetch tile kt+2 -> regs
            #pragma unroll
            for (int m = 0; m < 2; ++m) {
                int f = m * 512 + tid;
                kr[m] = *(const uint4*)(Kb + (size_t)((kt + 2) * 64 + (f >> 4)) * HD_ + (f & 15) * 8);
                vr[m] = *(const uint4*)(Vb + (size_t)(f >> 3) * S_ + (kt + 2) * 64 + (f & 7) * 8);
            }
        }

        f32x4 sacc[4] = {};
        __builtin_amdgcn_s_setprio(1);
        #pragma unroll
        for (int kk = 0; kk < 4; ++kk) {
            bf16x8 kf[4];
            #pragma unroll
            for (int n = 0; n < 4; ++n)
                kf[n] = *(const bf16x8*)&Kl[cur][n * 16 + ln][(kk * 32 + lg * 8) ^ swzP];
            #pragma unroll
            for (int n = 0; n < 4; ++n)
                sacc[n] = __builtin_amdgcn_mfma_f32_16x16x32_bf16(qf[kk], kf[n], sacc[n], 0, 0, 0);
        }
        __builtin_amdgcn_s_setprio(0);

        if (kt >= 2 * j) {                         // diagonal band: causal mask
            #pragma unroll
            for (int n = 0; n < 4; ++n)
                #pragma unroll
                for (int i = 0; i < 4; ++i) {
                    int kg = kt * 64 + n * 16 + ln;
                    if (kg > qg0 + i) sacc[n][i] = -1e30f;
                }
        }

        float mt[4];
        #pragma unroll
        for (int i = 0; i < 4; ++i) {
            mt[i] = fmaxf(fmaxf(sacc[0][i], sacc[1][i]), fmaxf(sacc[2][i], sacc[3][i]));
            #pragma unroll
            for (int d = 1; d < 16; d <<= 1)
                mt[i] = fmaxf(mt[i], __shfl_xor(mt[i], d));
        }
        // T13 defer-max: skip rescale when all tile maxima within +8 of running max
        bool ok = true;
        #pragma unroll
        for (int i = 0; i < 4; ++i) ok = ok && (mt[i] <= m_run[i] + 8.f);
        if (!__all(ok)) {
            #pragma unroll
            for (int i = 0; i < 4; ++i) {
                float mnew = fmaxf(m_run[i], mt[i]);
                float scale = __expf(m_run[i] - mnew);
                m_run[i] = mnew;
                l_run[i] *= scale;
                #pragma unroll
                for (int dn = 0; dn < 8; ++dn)
                    oacc[dn][i] *= scale;
            }
        }
        float rs[4] = {0.f, 0.f, 0.f, 0.f};
        #pragma unroll
        for (int n = 0; n < 4; ++n)
            #pragma unroll
            for (int i = 0; i < 4; ++i) {
                float p = __expf(sacc[n][i] - m_run[i]);
                sacc[n][i] = p;
                rs[i] += p;
            }
        // P -> per-wave LDS (swizzled rows)
        #pragma unroll
        for (int n = 0; n < 4; ++n)
            #pragma unroll
            for (int i = 0; i < 4; ++i)
                Pl[w][lg * 4 + i][(n * 16 + ln) ^ (((lg * 4 + i) & 7) * 8)] = (bf16)sacc[n][i];

        #pragma unroll
        for (int i = 0; i < 4; ++i) {
            #pragma unroll
            for (int d = 1; d < 16; d <<= 1)
                rs[i] += __shfl_xor(rs[i], d);
            l_run[i] += rs[i];
        }

        __builtin_amdgcn_s_setprio(1);
        #pragma unroll
        for (int kk = 0; kk < 2; ++kk) {
            bf16x8 pf = *(const bf16x8*)&Pl[w][ln][(kk * 32 + lg * 8) ^ swzP];
            #pragma unroll
            for (int dn = 0; dn < 8; ++dn) {
                bf16x8 vf = *(const bf16x8*)&Vl[cur][dn * 16 + ln][(kk * 32 + lg * 8) ^ swzP];
                oacc[dn] = __builtin_amdgcn_mfma_f32_16x16x32_bf16(pf, vf, oacc[dn], 0, 0, 0);
            }
        }
        __builtin_amdgcn_s_setprio(0);

        __syncthreads();                           // seals buf[cur^1] writes + buf[cur] reads
    }

    #pragma unroll
    for (int i = 0; i < 4; ++i) {
        float inv = 1.0f / l_run[i];
        int s = j * 128 + w * 16 + lg * 4 + i;
        #pragma unroll
        for (int dn = 0; dn < 8; ++dn) {
            int d = dn * 16 + ln;
            O[((size_t)(b * S_ + s)) * HID_ + h * HD_ + d] = (bf16)(oacc[dn][i] * inv);
        }
    }
}

extern "C" void kernel_launch(void* const* d_in, const int* in_sizes, int n_in,
                              void* d_out, int out_size, void* d_ws, size_t ws_size,
                              hipStream_t stream) {
    const float* X    = (const float*)d_in[0];
    const int*   pos  = (const int*)d_in[2];
    const float* Wq   = (const float*)d_in[3];
    const float* bq   = (const float*)d_in[4];
    const float* Wk   = (const float*)d_in[5];
    const float* bk   = (const float*)d_in[6];
    const float* Wv   = (const float*)d_in[7];
    const float* bv   = (const float*)d_in[8];
    const float* Wo   = (const float*)d_in[9];
    const float* bo   = (const float*)d_in[10];
    float* Out = (float*)d_out;

    char* ws = (char*)d_ws;
    bf16* Xb  = (bf16*)(ws + OFF_XB);
    bf16* Wqt = (bf16*)(ws + OFF_WQT);
    bf16* Wkt = (bf16*)(ws + OFF_WKT);
    bf16* Wvt = (bf16*)(ws + OFF_WVT);
    bf16* Wot = (bf16*)(ws + OFF_WOT);
    bf16* Qb  = (bf16*)(ws + OFF_QB);
    bf16* Kb  = (bf16*)(ws + OFF_KB);
    bf16* Vtb = (bf16*)(ws + OFF_VTB);
    bf16* Ab  = (bf16*)(ws + OFF_AB);

    cvt_x<<<(M_TOT * HID_) / (256 * 4), 256, 0, stream>>>(X, Xb);
    trans_w<<<dim3(32, 32, 4), 256, 0, stream>>>(Wq, Wk, Wv, Wo, Wqt, Wkt, Wvt, Wot);

    gemm_qkv<<<dim3(48, M_TOT / 128), 256, 0, stream>>>(Xb, Wqt, bq, bk, bv, pos, Qb);

    attn_k<<<dim3(512), 512, 0, stream>>>(Qb, Kb, Vtb, Ab);

    gemm_o<<<dim3(512), 256, 0, stream>>>(Ab, Wot, bo, Out);
}

// Round 28
// 314.440 us; speedup vs baseline: 1.0038x; 1.0028x over previous
//
#include <hip/hip_runtime.h>
#include <hip/hip_bf16.h>

typedef __bf16 bf16;
typedef bf16 bf16x4 __attribute__((ext_vector_type(4)));
typedef bf16 bf16x8 __attribute__((ext_vector_type(8)));
typedef float f32x4 __attribute__((ext_vector_type(4)));

#define B_ 2
#define S_ 2048
#define HID_ 2048
#define NH_ 16
#define HD_ 128
#define M_TOT (B_ * S_)          // 4096
#define RSCALE 0.08838834764831845f   // 1/sqrt(128)
#define LN10000_OVER_64 0.14391156f    // ln(10000)/64

// ---------------- ws layout (bytes) ----------------
#define OFF_XB   0ull
#define OFF_WQT  (OFF_XB  + (size_t)M_TOT*HID_*2)
#define OFF_WKT  (OFF_WQT + (size_t)HID_*HID_*2)   // Wqt/Wkt/Wvt contiguous
#define OFF_WVT  (OFF_WKT + (size_t)HID_*HID_*2)
#define OFF_WOT  (OFF_WVT + (size_t)HID_*HID_*2)
#define OFF_QB   (OFF_WOT + (size_t)HID_*HID_*2)   // Qb/Kb/Vtb contiguous
#define OFF_KB   (OFF_QB  + (size_t)M_TOT*HID_*2)
#define OFF_VTB  (OFF_KB  + (size_t)M_TOT*HID_*2)
#define OFF_AB   (OFF_VTB + (size_t)M_TOT*HID_*2)

// async global -> LDS, 16B per lane. LDS dest must be wave-uniform base.
__device__ __forceinline__ void gload16(const bf16* g, bf16* l) {
    typedef const __attribute__((address_space(1))) unsigned int gu32;
    typedef __attribute__((address_space(3))) unsigned int lu32;
    __builtin_amdgcn_global_load_lds((gu32*)g, (lu32*)l, 16, 0, 0);
}

// ---------------- cast X fp32 -> bf16 ----------------
__global__ __launch_bounds__(256) void cvt_x(const float* __restrict__ x,
                                             bf16* __restrict__ o) {
    size_t i = ((size_t)blockIdx.x * 256 + threadIdx.x) * 4;
    float4 v = *(const float4*)(x + i);
    bf16x4 r; r[0] = (bf16)v.x; r[1] = (bf16)v.y; r[2] = (bf16)v.z; r[3] = (bf16)v.w;
    *(bf16x4*)(o + i) = r;
}

// -------- transpose + cast W (K,N) fp32 -> Wt (N,K) bf16 --------
__global__ __launch_bounds__(256) void trans_w(const float* w0, const float* w1,
                                               const float* w2, const float* w3,
                                               bf16* o0, bf16* o1, bf16* o2, bf16* o3) {
    const float* W; bf16* O;
    switch (blockIdx.z) {
        case 0: W = w0; O = o0; break;
        case 1: W = w1; O = o1; break;
        case 2: W = w2; O = o2; break;
        default: W = w3; O = o3; break;
    }
    __shared__ float t[64][65];
    int tid = threadIdx.x;
    int nt0 = blockIdx.x * 64, kt0 = blockIdx.y * 64;
    #pragma unroll
    for (int p = 0; p < 4; ++p) {
        int r = p * 16 + (tid >> 4);
        int c = (tid & 15) * 4;
        float4 v = *(const float4*)(W + (size_t)(kt0 + r) * HID_ + nt0 + c);
        t[r][c + 0] = v.x; t[r][c + 1] = v.y; t[r][c + 2] = v.z; t[r][c + 3] = v.w;
    }
    __syncthreads();
    #pragma unroll
    for (int p = 0; p < 4; ++p) {
        int rr = p * 16 + (tid >> 4);
        int cc = (tid & 15) * 4;
        bf16x4 v;
        v[0] = (bf16)t[cc + 0][rr]; v[1] = (bf16)t[cc + 1][rr];
        v[2] = (bf16)t[cc + 2][rr]; v[3] = (bf16)t[cc + 3][rr];
        *(bf16x4*)(O + (size_t)(nt0 + rr) * HID_ + kt0 + cc) = v;
    }
}

// ---------------- fused QKV GEMM (m97 structure + T2 swizzle) ----------------
// sel==2 (V) epilogue routes the 128x128 tile through LDS (aliasing the dead
// staging buffers) so global stores are contiguous 16B runs instead of
// 2B/4KB-stride scatter.
__global__ __launch_bounds__(256) void gemm_qkv(const bf16* __restrict__ A,
                                                const bf16* __restrict__ Wt3,
                                                const float* __restrict__ bq,
                                                const float* __restrict__ bk,
                                                const float* __restrict__ bv,
                                                const int* __restrict__ pos_ids,
                                                bf16* __restrict__ out3) {
    __shared__ bf16 smem[2][128][64];     // [0]=Al, [1]=Bl; aliased as 128x128 V-tile
    bf16 (*Al)[64] = smem[0];
    bf16 (*Bl)[64] = smem[1];
    bf16* tile = &smem[0][0][0];          // 16384 elems = 128x128
    const int tid = threadIdx.x;
    const int l = tid & 63, w = tid >> 6;
    const int ln = l & 15, lg = l >> 4;
    const int bm = blockIdx.y;
    const int sel = blockIdx.x >> 4, bnn = blockIdx.x & 15;
    const bf16* Bt = Wt3 + (size_t)sel * HID_ * HID_ + (size_t)bnn * 128 * HID_;
    const float* bias = sel == 0 ? bq : (sel == 1 ? bk : bv);
    const int swz = (ln & 7) * 8;                  // read-side XOR (elements)

    f32x4 acc[2][8] = {};

    for (int k0 = 0; k0 < HID_; k0 += 64) {
        __syncthreads();
        #pragma unroll
        for (int j = 0; j < 4; ++j) {
            int r0 = w * 32 + j * 8;
            int r = r0 + (l >> 3);
            int c = (((l & 7) ^ ((l >> 3) & 7))) * 8;   // source-side swizzle
            gload16(A  + (size_t)(bm * 128 + r) * HID_ + k0 + c, &Al[r0][0]);
            gload16(Bt + (size_t)r * HID_ + k0 + c, &Bl[r0][0]);
        }
        __syncthreads();
        #pragma unroll
        for (int kk = 0; kk < 2; ++kk) {
            bf16x8 af[2], bfv[8];
            #pragma unroll
            for (int fm = 0; fm < 2; ++fm)
                af[fm] = *(const bf16x8*)&Al[w * 32 + fm * 16 + ln][(kk * 32 + lg * 8) ^ swz];
            #pragma unroll
            for (int fn = 0; fn < 8; ++fn)
                bfv[fn] = *(const bf16x8*)&Bl[fn * 16 + ln][(kk * 32 + lg * 8) ^ swz];
            #pragma unroll
            for (int fm = 0; fm < 2; ++fm)
                #pragma unroll
                for (int fn = 0; fn < 8; ++fn)
                    acc[fm][fn] = __builtin_amdgcn_mfma_f32_16x16x32_bf16(
                        af[fm], bfv[fn], acc[fm][fn], 0, 0, 0);
        }
    }

    if (sel == 2) {
        // ---- V epilogue: LDS transpose for coalesced V^T stores ----
        __syncthreads();                           // staging buffers now dead
        #pragma unroll
        for (int fm = 0; fm < 2; ++fm)
            #pragma unroll
            for (int i = 0; i < 4; ++i) {
                int s_local = w * 32 + fm * 16 + lg * 4 + i;
                #pragma unroll
                for (int fn = 0; fn < 8; ++fn) {
                    int d = fn * 16 + ln;
                    float v = acc[fm][fn][i] + bias[bnn * 128 + d];
                    tile[d * 128 + (s_local ^ ((d & 7) * 8))] = (bf16)v;
                }
            }
        __syncthreads();
        const int b = (bm * 128) >> 11;
        const int s_base = (bm * 128) & (S_ - 1);
        bf16* O = out3 + 2 * (size_t)M_TOT * HID_
                + ((size_t)(b * NH_ + bnn) * HD_) * S_;
        const int sc = tid & 15;                   // 8-elem chunk within 128-s row
        #pragma unroll
        for (int p = 0; p < 8; ++p) {
            int d = p * 16 + (tid >> 4);
            bf16x8 v = *(const bf16x8*)&tile[d * 128 + ((sc * 8) ^ ((d & 7) * 8))];
            *(bf16x8*)(O + (size_t)d * S_ + s_base + sc * 8) = v;
        }
        return;
    }

    #pragma unroll
    for (int fm = 0; fm < 2; ++fm) {
        #pragma unroll
        for (int i = 0; i < 4; ++i) {
            int m_g = bm * 128 + w * 32 + fm * 16 + lg * 4 + i;
            int b = m_g >> 11, s = m_g & (S_ - 1);
            int pos = pos_ids[m_g];
            pos = pos < 0 ? 0 : (pos > 4095 ? 4095 : pos);
            size_t base = ((size_t)(b * NH_ + bnn) * S_ + s) * HD_;
            bf16* O = out3 + (size_t)sel * M_TOT * HID_;
            #pragma unroll
            for (int fn = 0; fn < 4; ++fn) {
                int j = fn * 16 + ln;
                float x1 = acc[fm][fn][i]     + bias[bnn * 128 + j];
                float x2 = acc[fm][fn + 4][i] + bias[bnn * 128 + j + 64];
                float invf = __expf(-(float)j * LN10000_OVER_64);
                float ang = (float)pos * invf;
                float sn, cs;
                __sincosf(ang, &sn, &cs);
                float y1 = x1 * cs - x2 * sn;
                float y2 = x2 * cs + x1 * sn;
                if (sel == 0) { y1 *= RSCALE; y2 *= RSCALE; }
                O[base + j]      = (bf16)y1;
                O[base + j + 64] = (bf16)y2;
            }
        }
    }
}

// ---------------- O-projection GEMM (fp32 out, swizzle + XCD map) ----------------
__global__ __launch_bounds__(256) void gemm_o(const bf16* __restrict__ A,
                                              const bf16* __restrict__ Bt0,
                                              const float* __restrict__ bias,
                                              float* __restrict__ out) {
    __shared__ bf16 Al[128][64];
    __shared__ bf16 Bl[128][64];
    const int tid = threadIdx.x;
    const int l = tid & 63, w = tid >> 6;
    const int ln = l & 15, lg = l >> 4;
    const int id = blockIdx.x;
    const int xcd = id & 7, k = id >> 3;
    const int bn = xcd * 2 + (k & 1);
    const int bm = k >> 1;
    const bf16* Bt = Bt0 + (size_t)bn * 128 * HID_;
    const int swz = (ln & 7) * 8;

    f32x4 acc[2][8] = {};

    for (int k0 = 0; k0 < HID_; k0 += 64) {
        __syncthreads();
        #pragma unroll
        for (int j = 0; j < 4; ++j) {
            int r0 = w * 32 + j * 8;
            int r = r0 + (l >> 3);
            int c = (((l & 7) ^ ((l >> 3) & 7))) * 8;
            gload16(A  + (size_t)(bm * 128 + r) * HID_ + k0 + c, &Al[r0][0]);
            gload16(Bt + (size_t)r * HID_ + k0 + c, &Bl[r0][0]);
        }
        __syncthreads();
        #pragma unroll
        for (int kk = 0; kk < 2; ++kk) {
            bf16x8 af[2], bfv[8];
            #pragma unroll
            for (int fm = 0; fm < 2; ++fm)
                af[fm] = *(const bf16x8*)&Al[w * 32 + fm * 16 + ln][(kk * 32 + lg * 8) ^ swz];
            #pragma unroll
            for (int fn = 0; fn < 8; ++fn)
                bfv[fn] = *(const bf16x8*)&Bl[fn * 16 + ln][(kk * 32 + lg * 8) ^ swz];
            #pragma unroll
            for (int fm = 0; fm < 2; ++fm)
                #pragma unroll
                for (int fn = 0; fn < 8; ++fn)
                    acc[fm][fn] = __builtin_amdgcn_mfma_f32_16x16x32_bf16(
                        af[fm], bfv[fn], acc[fm][fn], 0, 0, 0);
        }
    }

    #pragma unroll
    for (int fm = 0; fm < 2; ++fm)
        #pragma unroll
        for (int i = 0; i < 4; ++i) {
            int m_g = bm * 128 + w * 32 + fm * 16 + lg * 4 + i;
            #pragma unroll
            for (int fn = 0; fn < 8; ++fn) {
                int n_g = bn * 128 + fn * 16 + ln;
                out[(size_t)m_g * HID_ + n_g] = acc[fm][fn][i] + bias[n_g];
            }
        }
}

// -------- flash attention: double-buffered, single-barrier, swizzled, defer-max --------
__global__ __launch_bounds__(512) void attn_k(const bf16* __restrict__ Q,
                                              const bf16* __restrict__ K,
                                              const bf16* __restrict__ Vt,
                                              bf16* __restrict__ O) {
    __shared__ bf16 Kl[2][64][128];
    __shared__ bf16 Vl[2][128][64];
    __shared__ bf16 Pl[8][16][64];
    const int tid = threadIdx.x;
    const int l = tid & 63, w = tid >> 6;          // 8 waves
    const int ln = l & 15, lg = l >> 4;
    const int bid = blockIdx.x;                    // 512 linear
    const int j  = 15 - (bid >> 5);                // heavy q-tiles first
    const int bh = bid & 31;
    const int nkt = 2 * j + 2;                     // 64-key tiles

    const bf16* Qb = Q  + (size_t)bh * S_ * HD_;
    const bf16* Kb = K  + (size_t)bh * S_ * HD_;
    const bf16* Vb = Vt + (size_t)bh * S_ * HD_;   // (HD, S) per bh
    const int b = bh >> 4, h = bh & (NH_ - 1);

    const int qrow = j * 128 + w * 16 + ln;
    const int qg0  = j * 128 + w * 16 + lg * 4;
    const int swzP = (ln & 7) * 8;

    bf16x8 qf[4];
    #pragma unroll
    for (int kk = 0; kk < 4; ++kk)
        qf[kk] = *(const bf16x8*)(Qb + (size_t)qrow * HD_ + kk * 32 + lg * 8);

    float m_run[4], l_run[4];
    #pragma unroll
    for (int i = 0; i < 4; ++i) { m_run[i] = -1e30f; l_run[i] = 0.f; }
    f32x4 oacc[8] = {};

    uint4 kr[2], vr[2];
    // ---- prologue: tile 0 -> regs -> buf0; tile 1 -> regs ----
    #pragma unroll
    for (int m = 0; m < 2; ++m) {
        int f = m * 512 + tid;
        kr[m] = *(const uint4*)(Kb + (size_t)(f >> 4) * HD_ + (f & 15) * 8);
        vr[m] = *(const uint4*)(Vb + (size_t)(f >> 3) * S_ + (f & 7) * 8);
    }
    #pragma unroll
    for (int m = 0; m < 2; ++m) {
        int f = m * 512 + tid;
        int r = f >> 4,  c = f & 15;
        int rv = f >> 3, cv = f & 7;
        *(uint4*)&Kl[0][r][(c ^ (r & 7)) * 8] = kr[m];
        *(uint4*)&Vl[0][rv][(cv ^ (rv & 7)) * 8] = vr[m];
    }
    if (nkt > 1) {
        #pragma unroll
        for (int m = 0; m < 2; ++m) {
            int f = m * 512 + tid;
            kr[m] = *(const uint4*)(Kb + (size_t)(64 + (f >> 4)) * HD_ + (f & 15) * 8);
            vr[m] = *(const uint4*)(Vb + (size_t)(f >> 3) * S_ + 64 + (f & 7) * 8);
        }
    }
    __syncthreads();

    for (int kt = 0; kt < nkt; ++kt) {
        const int cur = kt & 1;
        if (kt + 1 < nkt) {                        // write tile kt+1 -> other buf
            #pragma unroll
            for (int m = 0; m < 2; ++m) {
                int f = m * 512 + tid;
                int r = f >> 4,  c = f & 15;
                int rv = f >> 3, cv = f & 7;
                *(uint4*)&Kl[cur ^ 1][r][(c ^ (r & 7)) * 8] = kr[m];
                *(uint4*)&Vl[cur ^ 1][rv][(cv ^ (rv & 7)) * 8] = vr[m];
            }
        }
        if (kt + 2 < nkt) {                        // prefetch tile kt+2 -> regs
            #pragma unroll
            for (int m = 0; m < 2; ++m) {
                int f = m * 512 + tid;
                kr[m] = *(const uint4*)(Kb + (size_t)((kt + 2) * 64 + (f >> 4)) * HD_ + (f & 15) * 8);
                vr[m] = *(const uint4*)(Vb + (size_t)(f >> 3) * S_ + (kt + 2) * 64 + (f & 7) * 8);
            }
        }

        f32x4 sacc[4] = {};
        __builtin_amdgcn_s_setprio(1);
        #pragma unroll
        for (int kk = 0; kk < 4; ++kk) {
            bf16x8 kf[4];
            #pragma unroll
            for (int n = 0; n < 4; ++n)
                kf[n] = *(const bf16x8*)&Kl[cur][n * 16 + ln][(kk * 32 + lg * 8) ^ swzP];
            #pragma unroll
            for (int n = 0; n < 4; ++n)
                sacc[n] = __builtin_amdgcn_mfma_f32_16x16x32_bf16(qf[kk], kf[n], sacc[n], 0, 0, 0);
        }
        __builtin_amdgcn_s_setprio(0);

        if (kt >= 2 * j) {                         // diagonal band: causal mask
            #pragma unroll
            for (int n = 0; n < 4; ++n)
                #pragma unroll
                for (int i = 0; i < 4; ++i) {
                    int kg = kt * 64 + n * 16 + ln;
                    if (kg > qg0 + i) sacc[n][i] = -1e30f;
                }
        }

        float mt[4];
        #pragma unroll
        for (int i = 0; i < 4; ++i) {
            mt[i] = fmaxf(fmaxf(sacc[0][i], sacc[1][i]), fmaxf(sacc[2][i], sacc[3][i]));
            #pragma unroll
            for (int d = 1; d < 16; d <<= 1)
                mt[i] = fmaxf(mt[i], __shfl_xor(mt[i], d));
        }
        // T13 defer-max: skip rescale when all tile maxima within +8 of running max
        bool ok = true;
        #pragma unroll
        for (int i = 0; i < 4; ++i) ok = ok && (mt[i] <= m_run[i] + 8.f);
        if (!__all(ok)) {
            #pragma unroll
            for (int i = 0; i < 4; ++i) {
                float mnew = fmaxf(m_run[i], mt[i]);
                float scale = __expf(m_run[i] - mnew);
                m_run[i] = mnew;
                l_run[i] *= scale;
                #pragma unroll
                for (int dn = 0; dn < 8; ++dn)
                    oacc[dn][i] *= scale;
            }
        }
        float rs[4] = {0.f, 0.f, 0.f, 0.f};
        #pragma unroll
        for (int n = 0; n < 4; ++n)
            #pragma unroll
            for (int i = 0; i < 4; ++i) {
                float p = __expf(sacc[n][i] - m_run[i]);
                sacc[n][i] = p;
                rs[i] += p;
            }
        // P -> per-wave LDS (swizzled rows)
        #pragma unroll
        for (int n = 0; n < 4; ++n)
            #pragma unroll
            for (int i = 0; i < 4; ++i)
                Pl[w][lg * 4 + i][(n * 16 + ln) ^ (((lg * 4 + i) & 7) * 8)] = (bf16)sacc[n][i];

        #pragma unroll
        for (int i = 0; i < 4; ++i) {
            #pragma unroll
            for (int d = 1; d < 16; d <<= 1)
                rs[i] += __shfl_xor(rs[i], d);
            l_run[i] += rs[i];
        }

        __builtin_amdgcn_s_setprio(1);
        #pragma unroll
        for (int kk = 0; kk < 2; ++kk) {
            bf16x8 pf = *(const bf16x8*)&Pl[w][ln][(kk * 32 + lg * 8) ^ swzP];
            #pragma unroll
            for (int dn = 0; dn < 8; ++dn) {
                bf16x8 vf = *(const bf16x8*)&Vl[cur][dn * 16 + ln][(kk * 32 + lg * 8) ^ swzP];
                oacc[dn] = __builtin_amdgcn_mfma_f32_16x16x32_bf16(pf, vf, oacc[dn], 0, 0, 0);
            }
        }
        __builtin_amdgcn_s_setprio(0);

        __syncthreads();                           // seals buf[cur^1] writes + buf[cur] reads
    }

    #pragma unroll
    for (int i = 0; i < 4; ++i) {
        float inv = 1.0f / l_run[i];
        int s = j * 128 + w * 16 + lg * 4 + i;
        #pragma unroll
        for (int dn = 0; dn < 8; ++dn) {
            int d = dn * 16 + ln;
            O[((size_t)(b * S_ + s)) * HID_ + h * HD_ + d] = (bf16)(oacc[dn][i] * inv);
        }
    }
}

extern "C" void kernel_launch(void* const* d_in, const int* in_sizes, int n_in,
                              void* d_out, int out_size, void* d_ws, size_t ws_size,
                              hipStream_t stream) {
    const float* X    = (const float*)d_in[0];
    const int*   pos  = (const int*)d_in[2];
    const float* Wq   = (const float*)d_in[3];
    const float* bq   = (const float*)d_in[4];
    const float* Wk   = (const float*)d_in[5];
    const float* bk   = (const float*)d_in[6];
    const float* Wv   = (const float*)d_in[7];
    const float* bv   = (const float*)d_in[8];
    const float* Wo   = (const float*)d_in[9];
    const float* bo   = (const float*)d_in[10];
    float* Out = (float*)d_out;

    char* ws = (char*)d_ws;
    bf16* Xb  = (bf16*)(ws + OFF_XB);
    bf16* Wqt = (bf16*)(ws + OFF_WQT);
    bf16* Wkt = (bf16*)(ws + OFF_WKT);
    bf16* Wvt = (bf16*)(ws + OFF_WVT);
    bf16* Wot = (bf16*)(ws + OFF_WOT);
    bf16* Qb  = (bf16*)(ws + OFF_QB);
    bf16* Kb  = (bf16*)(ws + OFF_KB);
    bf16* Vtb = (bf16*)(ws + OFF_VTB);
    bf16* Ab  = (bf16*)(ws + OFF_AB);

    cvt_x<<<(M_TOT * HID_) / (256 * 4), 256, 0, stream>>>(X, Xb);
    trans_w<<<dim3(32, 32, 4), 256, 0, stream>>>(Wq, Wk, Wv, Wo, Wqt, Wkt, Wvt, Wot);

    gemm_qkv<<<dim3(48, M_TOT / 128), 256, 0, stream>>>(Xb, Wqt, bq, bk, bv, pos, Qb);

    attn_k<<<dim3(512), 512, 0, stream>>>(Qb, Kb, Vtb, Ab);

    gemm_o<<<dim3(512), 256, 0, stream>>>(Ab, Wot, bo, Out);
}